// Round 4
// baseline (556.701 us; speedup 1.0000x reference)
//
#include <hip/hip_runtime.h>

// ================= degree =================

__global__ void k_count(const int* __restrict__ dst, int* __restrict__ cnt, int e) {
    int i = blockIdx.x * blockDim.x + threadIdx.x;
    if (i < e) atomicAdd(&cnt[dst[i]], 1);
}

// ---- 3-phase scan over cnt -> rowptr/cursor (+ dinv fused) ----
#define SCP 1024

__global__ void k_scan_a(const int* __restrict__ cnt, int* __restrict__ part, int n) {
    int p = blockIdx.x * blockDim.x + threadIdx.x;
    if (p >= SCP) return;
    int chunk = (n + SCP - 1) / SCP;
    int b = p * chunk, e = min(b + chunk, n), s = 0;
    for (int i = b; i < e; ++i) s += cnt[i];
    part[p] = s;
}

__global__ void k_scan_b(int* __restrict__ part) {   // 1 block, 1024 threads
    __shared__ int sm[SCP];
    int t = threadIdx.x;
    sm[t] = part[t];
    __syncthreads();
    for (int off = 1; off < SCP; off <<= 1) {
        int v = (t >= off) ? sm[t - off] : 0;
        __syncthreads();
        sm[t] += v;
        __syncthreads();
    }
    part[t] = t ? sm[t - 1] : 0;   // exclusive
}

__global__ void k_scan_c(const int* __restrict__ cnt, const int* __restrict__ part,
                         int* __restrict__ rowptr, int* __restrict__ cursor,
                         float* __restrict__ dinv, int n) {
    int p = blockIdx.x * blockDim.x + threadIdx.x;
    if (p >= SCP) return;
    int chunk = (n + SCP - 1) / SCP;
    int b = p * chunk, e = min(b + chunk, n);
    int run = part[p];
    for (int i = b; i < e; ++i) {
        rowptr[i] = run;
        cursor[i] = run;
        dinv[i] = rsqrtf((float)(cnt[i] + 1));   // +1 self-loop
        run += cnt[i];
    }
    if (p == SCP - 1) rowptr[n] = run;
}

__global__ void k_fill(const int* __restrict__ src, const int* __restrict__ dstv,
                       int* __restrict__ cursor, int* __restrict__ csr_src, int e) {
    int i = blockIdx.x * blockDim.x + threadIdx.x;
    if (i < e) {
        int pos = atomicAdd(&cursor[dstv[i]], 1);
        csr_src[pos] = src[i];
    }
}

// ================= GEMM: C[row] = dinv[row] * (A[row] @ W)  =================
// LDS-tiled register-blocked fp32 GEMM. BM=128 rows/block, BK=32 k-slab.
// 256 threads as 16x16; thread tile = 8 rows x TN cols (TN = COUT/16).

template<int COUT>
__global__ __launch_bounds__(256) void k_gemm(const float* __restrict__ A,
                                              const float* __restrict__ W,
                                              const float* __restrict__ dinv,
                                              float* __restrict__ C, int n) {
    const int BM = 128, BK = 32;
    const int TN = COUT / 16;                 // 8 (COUT=128) or 4 (COUT=64)
    __shared__ float sA[BK][BM + 4];
    __shared__ float sW[BK][COUT + 4];

    int tid = threadIdx.x;
    int row0 = blockIdx.x * BM;
    int tr = tid & 15, tc = tid >> 4;
    int r0 = tr * 8, c0 = tc * TN;

    float acc[8][TN];
#pragma unroll
    for (int i = 0; i < 8; ++i)
#pragma unroll
        for (int j = 0; j < TN; ++j) acc[i][j] = 0.f;

    for (int slab = 0; slab < 4; ++slab) {
#pragma unroll
        for (int t = 0; t < 4; ++t) {
            int f = tid + t * 256;            // 1024 float4s
            int row = f >> 3, k4 = f & 7;
            int gr = min(row0 + row, n - 1);
            float4 v = *reinterpret_cast<const float4*>(A + (long)gr * 128 + slab * 32 + k4 * 4);
            sA[k4 * 4 + 0][row] = v.x;
            sA[k4 * 4 + 1][row] = v.y;
            sA[k4 * 4 + 2][row] = v.z;
            sA[k4 * 4 + 3][row] = v.w;
        }
        const int WF4 = BK * COUT / 4;
        for (int f = tid; f < WF4; f += 256) {
            int k = f / (COUT / 4), c4 = (f % (COUT / 4)) * 4;
            float4 v = *reinterpret_cast<const float4*>(W + (long)(slab * 32 + k) * COUT + c4);
            *reinterpret_cast<float4*>(&sW[k][c4]) = v;
        }
        __syncthreads();

#pragma unroll
        for (int k = 0; k < BK; ++k) {
            float a[8], w[TN];
            *reinterpret_cast<float4*>(&a[0]) = *reinterpret_cast<const float4*>(&sA[k][r0]);
            *reinterpret_cast<float4*>(&a[4]) = *reinterpret_cast<const float4*>(&sA[k][r0 + 4]);
#pragma unroll
            for (int j = 0; j < TN; j += 4)
                *reinterpret_cast<float4*>(&w[j]) = *reinterpret_cast<const float4*>(&sW[k][c0 + j]);
#pragma unroll
            for (int i = 0; i < 8; ++i)
#pragma unroll
                for (int j = 0; j < TN; ++j)
                    acc[i][j] = fmaf(a[i], w[j], acc[i][j]);
        }
        __syncthreads();
    }

#pragma unroll
    for (int i = 0; i < 8; ++i) {
        int row = row0 + r0 + i;
        if (row < n) {
            float dv = dinv[row];
#pragma unroll
            for (int j = 0; j < TN; ++j) acc[i][j] *= dv;
#pragma unroll
            for (int j = 0; j < TN; j += 4)
                *reinterpret_cast<float4*>(C + (long)row * COUT + c0 + j) =
                    *reinterpret_cast<float4*>(&acc[i][j]);
        }
    }
}

// ================= pull aggregation =================
// out[d] = act( dinv[d] * ( ht[d] + sum_{s in N(d)} ht[s] ) + bias ),  ht pre-scaled by dinv.

template<int C, bool RELU>
__global__ void k_gather(const int* __restrict__ rowptr, const int* __restrict__ csr_src,
                         const float* __restrict__ dinv, const float* __restrict__ h,
                         const float* __restrict__ bias, float* __restrict__ out, int n) {
    const int TPN = C / 4;
    int t = blockIdx.x * blockDim.x + threadIdx.x;
    int node = t / TPN;
    if (node >= n) return;
    int c = (t % TPN) * 4;

    const float4* h4 = reinterpret_cast<const float4*>(h);
    float4 acc = h4[((long)node * C + c) >> 2];   // self-loop term (already dinv-scaled)

    int beg = rowptr[node], end = rowptr[node + 1];
    int e = beg;
    for (; e + 4 <= end; e += 4) {
        int s0 = csr_src[e + 0], s1 = csr_src[e + 1];
        int s2 = csr_src[e + 2], s3 = csr_src[e + 3];
        float4 u0 = h4[((long)s0 * C + c) >> 2];
        float4 u1 = h4[((long)s1 * C + c) >> 2];
        float4 u2 = h4[((long)s2 * C + c) >> 2];
        float4 u3 = h4[((long)s3 * C + c) >> 2];
        acc.x += u0.x + u1.x + u2.x + u3.x;
        acc.y += u0.y + u1.y + u2.y + u3.y;
        acc.z += u0.z + u1.z + u2.z + u3.z;
        acc.w += u0.w + u1.w + u2.w + u3.w;
    }
    for (; e < end; ++e) {
        int s = csr_src[e];
        float4 u = h4[((long)s * C + c) >> 2];
        acc.x += u.x; acc.y += u.y; acc.z += u.z; acc.w += u.w;
    }
    float dd = dinv[node];
    float4 b4 = *reinterpret_cast<const float4*>(bias + c);
    acc.x = fmaf(acc.x, dd, b4.x);
    acc.y = fmaf(acc.y, dd, b4.y);
    acc.z = fmaf(acc.z, dd, b4.z);
    acc.w = fmaf(acc.w, dd, b4.w);
    if (RELU) {
        acc.x = fmaxf(acc.x, 0.f); acc.y = fmaxf(acc.y, 0.f);
        acc.z = fmaxf(acc.z, 0.f); acc.w = fmaxf(acc.w, 0.f);
    }
    reinterpret_cast<float4*>(out)[((long)node * C + c) >> 2] = acc;
}

// ================= decode =================

__global__ void k_decode(const int* __restrict__ ia, const int* __restrict__ ib,
                         const float* __restrict__ z, float* __restrict__ out, int m) {
    int t = blockIdx.x * blockDim.x + threadIdx.x;
    int k = t / 16;
    if (k >= m) return;
    int c = (t & 15) * 4;
    int a = ia[k], b = ib[k];
    float4 va = *reinterpret_cast<const float4*>(z + (long)a * 64 + c);
    float4 vb = *reinterpret_cast<const float4*>(z + (long)b * 64 + c);
    float dot = va.x * vb.x + va.y * vb.y + va.z * vb.z + va.w * vb.w;
    dot += __shfl_xor(dot, 8);
    dot += __shfl_xor(dot, 4);
    dot += __shfl_xor(dot, 2);
    dot += __shfl_xor(dot, 1);
    if ((t & 15) == 0) out[k] = dot;
}

// ================= launcher =================

extern "C" void kernel_launch(void* const* d_in, const int* in_sizes, int n_in,
                              void* d_out, int out_size, void* d_ws, size_t ws_size,
                              hipStream_t stream) {
    const float* x  = (const float*)d_in[0];
    const int*   ei = (const int*)d_in[1];
    const int*   el = (const int*)d_in[2];
    const float* W1 = (const float*)d_in[3];
    const float* b1 = (const float*)d_in[4];
    const float* W2 = (const float*)d_in[5];
    const float* b2 = (const float*)d_in[6];
    float* out = (float*)d_out;

    const int N = in_sizes[0] / 128;
    const int E = in_sizes[1] / 2;
    const int L = out_size;

    const int* src = ei;
    const int* dst = ei + E;
    const int* la  = el;
    const int* lb  = el + L;

    // ---- workspace layout ----
    float* bufA = (float*)d_ws;                     // N*128
    float* bufB = bufA + (long)N * 128;             // N*128
    int*   csr_src = (int*)(bufB + (long)N * 128);  // E
    int*   cnt     = csr_src + E;                   // N
    int*   rowptr  = cnt + N;                       // N+1
    int*   cursor  = rowptr + N + 1;                // N
    float* dinv    = (float*)(cursor + N);          // N
    int*   part    = (int*)(dinv + N);              // SCP
    float* z    = bufA;                             // N*64 (reuse)
    float* zout = bufA + (long)N * 64;              // N*64 (reuse)

    auto cdiv = [](long a, long b) { return (int)((a + b - 1) / b); };

    // ---- CSR build + normalization ----
    hipMemsetAsync(cnt, 0, (size_t)N * sizeof(int), stream);
    k_count <<<cdiv(E, 256), 256, 0, stream>>>(dst, cnt, E);
    k_scan_a<<<SCP / 256, 256, 0, stream>>>(cnt, part, N);
    k_scan_b<<<1, SCP, 0, stream>>>(part);
    k_scan_c<<<SCP / 256, 256, 0, stream>>>(cnt, part, rowptr, cursor, dinv, N);
    k_fill  <<<cdiv(E, 256), 256, 0, stream>>>(src, dst, cursor, csr_src, E);

    // ---- layer 1: h = relu(agg(x @ W1) + b1) ----
    k_gemm<128><<<cdiv(N, 128), 256, 0, stream>>>(x, W1, dinv, bufA, N);
    k_gather<128, true><<<cdiv((long)N * 32, 256), 256, 0, stream>>>(
        rowptr, csr_src, dinv, bufA, b1, bufB, N);

    // ---- layer 2: z = agg(h @ W2) + b2 ----
    k_gemm<64><<<cdiv(N, 128), 256, 0, stream>>>(bufB, W2, dinv, z, N);
    k_gather<64, false><<<cdiv((long)N * 16, 256), 256, 0, stream>>>(
        rowptr, csr_src, dinv, z, b2, zout, N);

    // ---- decode ----
    k_decode<<<cdiv((long)L * 16, 256), 256, 0, stream>>>(la, lb, zout, out, L);
}